// Round 1
// baseline (85.331 us; speedup 1.0000x reference)
//
#include <hip/hip_runtime.h>

// out[s,i] = Re( U x_s ), reverse-order transposed-gate statevector sim.
// R14 = R13 with the f16 state path removed:
//  - LDS state is f32 (f2 per element); element-index space == R13's
//    word-index space, so ALL layout constants (cA/cC/SRC/CB1/CC2/CC3/CWA),
//    the sigma fold, and the barrier-free single-wave structure are
//    byte-identical to R13. Reads b64->b128, RT3/init writes b32->b64.
//  - removes ~70 cvt/pack VALU ops per stage (up2/pk2 gone).
//  - uniform gate reads: 2 vector ds_read broadcasts per level instead of
//    7 scalar ds_reads.
// Conflict-freedom preserved: b128 quad-bank index = old word bits 1-3,
// rank-3 balanced for every RT access (optimal 8 clk for wave64 b128).

#define NQ 10
#define NL 5
#define NTH 64

typedef float f2 __attribute__((ext_vector_type(2)));
typedef float f4 __attribute__((ext_vector_type(4)));
typedef unsigned int u32;

// ----- composed reversed ring-CNOT permutation (verified R3-R13), linear.
constexpr int csigma(int i) {
  for (int q = 0; q < NQ; ++q) {
    const int cb = 9 - q, tb = 9 - ((q + 1) % NQ);
    i ^= ((i >> cb) & 1) << tb;
  }
  return i;
}

// Layout-A block index (9 bits, linear, kernel {0,511}):
constexpr int cA(int s) {
  return ((s ^ (s >> 4)) & 1) | ((((s >> 1) ^ (s >> 5)) & 1) << 1) |
         ((((s >> 2) ^ (s >> 6)) & 1) << 2) |
         ((((s >> 3) ^ (s >> 7)) & 1) << 3) |
         ((((s >> 4) ^ (s >> 8)) & 1) << 4) | (((s ^ (s >> 1)) & 1) << 5) |
         ((((s >> 1) ^ (s >> 2)) & 1) << 6) |
         ((((s >> 2) ^ (s >> 3)) & 1) << 7) | (((s >> 9) & 1) << 8);
}
// Layout-C block index (linear, bijective on 9 bits):
constexpr int cC(int p) {
  return ((p >> 6) & 7) | (((p ^ (p >> 3)) & 1) << 3) |
         ((((p >> 1) ^ (p >> 4)) & 1) << 4) | (((p >> 2) & 1) << 5) |
         (((p >> 3) & 1) << 6) | (((p >> 4) & 1) << 7) | (((p >> 5) & 1) << 8);
}

// packed SoA butterfly: two independent complex bflys, component-wise.
__device__ __forceinline__ void pbfly(f2& aRe, f2& aIm, f2& bRe, f2& bIm,
                                      float h00, float h01x, float h01y,
                                      float h10x, float h10y, float h11x,
                                      float h11y) {
  const f2 naRe = h00 * aRe + h01x * bRe - h01y * bIm;
  const f2 naIm = h00 * aIm + h01x * bIm + h01y * bRe;
  const f2 nbRe = h10x * aRe - h10y * aIm + h11x * bRe - h11y * bIm;
  const f2 nbIm = h10x * aIm + h10y * aRe + h11x * bIm + h11y * bRe;
  aRe = naRe; aIm = naIm; bRe = nbRe; bIm = nbIm;
}

__global__ __launch_bounds__(NTH) void qc_apply(
    const float* __restrict__ x, const float* __restrict__ wts,
    float* __restrict__ out, int out_size) {
  __shared__ alignas(16) f2 scf[1024];           // state: f32 (re,im)/element
  __shared__ alignas(16) float sg[NL * NQ * 8];  // gate table, f32

  const int t = threadIdx.x;
  const int sv = blockIdx.x;

  // ---- in-kernel gate build (lanes < 50): transposed U3, h00 real.
  // Same-wave DS ordering: these ds_writes precede all sg reads in program
  // order -> visible without a barrier (validated R12/R13 passes).
  if (t < NL * NQ) {
    const float th = wts[t * 3 + 0], ph = wts[t * 3 + 1], lm = wts[t * 3 + 2];
    const float ch_ = __cosf(0.5f * th), sh = __sinf(0.5f * th);
    const float cl = __cosf(lm), sl = __sinf(lm);
    const float cp = __cosf(ph), sp = __sinf(ph);
    const float cpl = __cosf(ph + lm), spl = __sinf(ph + lm);
    float* G = sg + t * 8;
    G[0] = ch_;       G[1] = 0.0f;
    G[2] = cp * sh;   G[3] = sp * sh;
    G[4] = -cl * sh;  G[5] = -sl * sh;
    G[6] = cpl * ch_; G[7] = spl * ch_;
  }

  // ---- runtime sigma(t) and hoisted address bases (identical to R13).
  int st = t;
#pragma unroll
  for (int q = 0; q < NQ; ++q) {
    const int cb = 9 - q, tb = 9 - ((q + 1) % NQ);
    st ^= ((st >> cb) & 1) << tb;
  }
  const int baseS = cA(st) << 1;                 // sigma-read base (layout A)
  const int tb1 = t << 1;                        // RT1-write base (layout B)
  const int tb2 = (((t & 7) | ((t >> 3) << 6)) ^ ((((t >> 3) & 3)) << 3)) << 1;
  const int tc2 = cC((t & 7) | ((t >> 3) << 6)) << 1;  // RT2-write base (C)
  const int tc3 = cC(t << 3) << 1;               // RT3-read base (C)
  const int ta3 = cA(t << 3) << 1;               // RT3-write base (A)

  static constexpr int SRC[8] = {
      cA(csigma(0 << 6)) << 1, cA(csigma(1 << 6)) << 1, cA(csigma(2 << 6)) << 1,
      cA(csigma(3 << 6)) << 1, cA(csigma(4 << 6)) << 1, cA(csigma(5 << 6)) << 1,
      cA(csigma(6 << 6)) << 1, cA(csigma(7 << 6)) << 1};
#define CB1v(r) ((((r) << 6) ^ (((r) & 3) << 3)) << 1)
  static constexpr int CB1[8] = {CB1v(0), CB1v(1), CB1v(2), CB1v(3),
                                 CB1v(4), CB1v(5), CB1v(6), CB1v(7)};
  static constexpr int CC2[8] = {cC(0 << 3) << 1, cC(1 << 3) << 1,
                                 cC(2 << 3) << 1, cC(3 << 3) << 1,
                                 cC(4 << 3) << 1, cC(5 << 3) << 1,
                                 cC(6 << 3) << 1, cC(7 << 3) << 1};
  static constexpr int CC3[8] = {cC(0) << 1, cC(1) << 1, cC(2) << 1,
                                 cC(3) << 1, cC(4) << 1, cC(5) << 1,
                                 cC(6) << 1, cC(7) << 1};
  static constexpr int CWA[8] = {
      (cA(0) << 1) | 0, (cA(1) << 1) | 1, (cA(2) << 1) | 0, (cA(3) << 1) | 1,
      (cA(4) << 1) | 0, (cA(5) << 1) | 1, (cA(6) << 1) | 0, (cA(7) << 1) | 1};
  static constexpr int CAj[16] = {cA(0),  cA(1),  cA(2),  cA(3),
                                  cA(4),  cA(5),  cA(6),  cA(7),
                                  cA(8),  cA(9),  cA(10), cA(11),
                                  cA(12), cA(13), cA(14), cA(15)};

  // ---- init: x real -> layout A f32 (state s at elem 2*A(s)+h(s), h=s0^s9).
  {
    const float* xs = x + (size_t)sv * 1024;
    float4 xv[4];
#pragma unroll
    for (int i4 = 0; i4 < 4; ++i4) xv[i4] = ((const float4*)xs)[4 * t + i4];
    const int ib2 = cA(16 * t) << 1;
    const int ihb = (t >> 5) & 1;  // h(16t) = s9 = t5
#pragma unroll
    for (int j = 0; j < 16; ++j) {
      const float xj = ((const float*)xv)[j];
      const int el = (ib2 ^ (CAj[j] << 1)) | (ihb ^ (j & 1));
      scf[el] = (f2){xj, 0.0f};
    }
  }

  f2 vre[8], vim[8];

  for (int l = NL - 1; l >= 0; --l) {
    const float* gl = sg + l * NQ * 8;   // LDS pointer: uniform ds_read bcast

    // ======== RT1: sigma-gather (layout A); reg bits = SV bits 6-8.
#pragma unroll
    for (int r = 0; r < 8; ++r) {
      const f4 q = *(const f4*)&scf[baseS ^ SRC[r]];  // elems {W,W+1}=(re,im)
      vre[r] = (f2){q.x, q.z};
      vim[r] = (f2){q.y, q.w};
    }
    {
      const int qb[3] = {3, 2, 1};  // reg bit e = SV bit 6+e <-> qubit 3-e
#pragma unroll
      for (int e = 0; e < 3; ++e) {
        const float* G = gl + qb[e] * 8;
        const f4 ga = *(const f4*)&G[0];
        const f4 gb = *(const f4*)&G[4];
        const float h00 = ga.x, h01x = ga.z, h01y = ga.w, h10x = gb.x,
                    h10y = gb.y, h11x = gb.z, h11y = gb.w;
        const int m = 1 << e;
#pragma unroll
        for (int r = 0; r < 8; ++r)
          if (!(r & m))
            pbfly(vre[r], vim[r], vre[r | m], vim[r | m], h00, h01x, h01y,
                  h10x, h10y, h11x, h11y);
      }
    }
#pragma unroll
    for (int r = 0; r < 8; ++r) {  // elem E=(re-pair), E+1=(im-pair)
      *(f4*)&scf[tb1 ^ CB1[r]] =
          (f4){vre[r].x, vre[r].y, vim[r].x, vim[r].y};
    }

    // ======== RT2 (layout B -> C); reg bits = SV bits 3-5.
#pragma unroll
    for (int r = 0; r < 8; ++r) {
      const f4 q = *(const f4*)&scf[tb2 ^ (r << 4)];
      vre[r] = (f2){q.x, q.y};
      vim[r] = (f2){q.z, q.w};
    }
    {
      const int qb[3] = {6, 5, 4};  // reg bit e = SV bit 3+e <-> qubit 6-e
#pragma unroll
      for (int e = 0; e < 3; ++e) {
        const float* G = gl + qb[e] * 8;
        const f4 ga = *(const f4*)&G[0];
        const f4 gb = *(const f4*)&G[4];
        const float h00 = ga.x, h01x = ga.z, h01y = ga.w, h10x = gb.x,
                    h10y = gb.y, h11x = gb.z, h11y = gb.w;
        const int m = 1 << e;
#pragma unroll
        for (int r = 0; r < 8; ++r)
          if (!(r & m))
            pbfly(vre[r], vim[r], vre[r | m], vim[r | m], h00, h01x, h01y,
                  h10x, h10y, h11x, h11y);
      }
    }
#pragma unroll
    for (int r = 0; r < 8; ++r) {
      *(f4*)&scf[tc2 ^ CC2[r]] =
          (f4){vre[r].x, vre[r].y, vim[r].x, vim[r].y};
    }

    // ======== RT3 (layout C); reg bits = SV bits 0-2, + bit-9 gate.
#pragma unroll
    for (int r = 0; r < 8; ++r) {
      const f4 q = *(const f4*)&scf[tc3 ^ CC3[r]];
      vre[r] = (f2){q.x, q.y};
      vim[r] = (f2){q.z, q.w};
    }
    {
      const int qb[3] = {9, 8, 7};  // reg bit e = SV bit e <-> qubit 9-e
#pragma unroll
      for (int e = 0; e < 3; ++e) {
        const float* G = gl + qb[e] * 8;
        const f4 ga = *(const f4*)&G[0];
        const f4 gb = *(const f4*)&G[4];
        const float h00 = ga.x, h01x = ga.z, h01y = ga.w, h10x = gb.x,
                    h10y = gb.y, h11x = gb.z, h11y = gb.w;
        const int m = 1 << e;
#pragma unroll
        for (int r = 0; r < 8; ++r)
          if (!(r & m))
            pbfly(vre[r], vim[r], vre[r | m], vim[r | m], h00, h01x, h01y,
                  h10x, h10y, h11x, h11y);
      }
    }
    {  // qubit-0 gate on SV bit 9 = pack halves (.x <-> .y), scalar form.
      const float* G = gl;
      const f4 ga = *(const f4*)&G[0];
      const f4 gb = *(const f4*)&G[4];
      const float h00 = ga.x, h01x = ga.z, h01y = ga.w, h10x = gb.x,
                  h10y = gb.y, h11x = gb.z, h11y = gb.w;
#pragma unroll
      for (int r = 0; r < 8; ++r) {
        const float re0 = vre[r].x, im0 = vim[r].x;
        const float re1 = vre[r].y, im1 = vim[r].y;
        vre[r].x = h00 * re0 + h01x * re1 - h01y * im1;
        vim[r].x = h00 * im0 + h01x * im1 + h01y * re1;
        vre[r].y = h10x * re0 - h10y * im0 + h11x * re1 - h11y * im1;
        vim[r].y = h10x * im0 + h10y * re0 + h11x * im1 + h11y * re1;
      }
    }
    if (l != 0) {
#pragma unroll
      for (int r = 0; r < 8; ++r) {
        const int w0 = ta3 ^ CWA[r];
        scf[w0] = (f2){vre[r].x, vim[r].x};
        scf[w0 ^ 513] = (f2){vre[r].y, vim[r].y};
      }
    }
  }

  // ---- output: reals only. .x -> indices 8t..8t+7, .y -> +512.
  const size_t ob = (size_t)sv * 1024 + 8 * t;
  if (ob + 8 <= (size_t)out_size) {
    *(float4*)(out + ob) = make_float4(vre[0].x, vre[1].x, vre[2].x, vre[3].x);
    *(float4*)(out + ob + 4) =
        make_float4(vre[4].x, vre[5].x, vre[6].x, vre[7].x);
  }
  if (ob + 512 + 8 <= (size_t)out_size) {
    *(float4*)(out + ob + 512) =
        make_float4(vre[0].y, vre[1].y, vre[2].y, vre[3].y);
    *(float4*)(out + ob + 516) =
        make_float4(vre[4].y, vre[5].y, vre[6].y, vre[7].y);
  }
}

extern "C" void kernel_launch(void* const* d_in, const int* in_sizes, int n_in,
                              void* d_out, int out_size, void* d_ws, size_t ws_size,
                              hipStream_t stream) {
  const float* x = (const float*)d_in[0];   // [128,16,32,32] f32
  const float* w = (const float*)d_in[1];   // [5,10,3] f32
  float* out = (float*)d_out;               // f32 (real part of complex64)
  const int nstates = in_sizes[0] / 1024;   // 2048
  qc_apply<<<nstates, NTH, 0, stream>>>(x, w, out, out_size);
}

// Round 2
// 81.383 us; speedup vs baseline: 1.0485x; 1.0485x over previous
//
#include <hip/hip_runtime.h>
#include <hip/hip_fp16.h>

// out[s,i] = Re( U x_s ), reverse-order transposed-gate statevector sim.
// R15 = R13 (f16 LDS state, verified fastest DS configuration) +
//  - R14's vectorized gate reads: 2x ds_read_b128 per gate level instead
//    of 7x scalar ds_read_b32 (saves ~250 DS issues/block on the pipe the
//    R13<->R14 A/B proved is the bottleneck). f4 gate mapping verified by
//    R14's pass.
//  - dead-vim skip in the final (l==0) qubit-0 stage (vim unused after).
// Everything else (layouts, sigma fold, SoA pack on bit 9, f16 LDS state,
// barrier-free single-wave blocks) is byte-identical to R13.

#define NQ 10
#define NL 5
#define NTH 64

typedef float f2 __attribute__((ext_vector_type(2)));
typedef float f4 __attribute__((ext_vector_type(4)));
typedef unsigned int u32;

// ----- composed reversed ring-CNOT permutation (verified R3-R14), linear.
constexpr int csigma(int i) {
  for (int q = 0; q < NQ; ++q) {
    const int cb = 9 - q, tb = 9 - ((q + 1) % NQ);
    i ^= ((i >> cb) & 1) << tb;
  }
  return i;
}

// Layout-A block index (9 bits, linear, kernel {0,511}):
constexpr int cA(int s) {
  return ((s ^ (s >> 4)) & 1) | ((((s >> 1) ^ (s >> 5)) & 1) << 1) |
         ((((s >> 2) ^ (s >> 6)) & 1) << 2) |
         ((((s >> 3) ^ (s >> 7)) & 1) << 3) |
         ((((s >> 4) ^ (s >> 8)) & 1) << 4) | (((s ^ (s >> 1)) & 1) << 5) |
         ((((s >> 1) ^ (s >> 2)) & 1) << 6) |
         ((((s >> 2) ^ (s >> 3)) & 1) << 7) | (((s >> 9) & 1) << 8);
}
// Layout-C block index (linear, bijective on 9 bits):
constexpr int cC(int p) {
  return ((p >> 6) & 7) | (((p ^ (p >> 3)) & 1) << 3) |
         ((((p >> 1) ^ (p >> 4)) & 1) << 4) | (((p >> 2) & 1) << 5) |
         (((p >> 3) & 1) << 6) | (((p >> 4) & 1) << 7) | (((p >> 5) & 1) << 8);
}

// packed SoA butterfly: two independent complex bflys, component-wise.
__device__ __forceinline__ void pbfly(f2& aRe, f2& aIm, f2& bRe, f2& bIm,
                                      float h00, float h01x, float h01y,
                                      float h10x, float h10y, float h11x,
                                      float h11y) {
  const f2 naRe = h00 * aRe + h01x * bRe - h01y * bIm;
  const f2 naIm = h00 * aIm + h01x * bIm + h01y * bRe;
  const f2 nbRe = h10x * aRe - h10y * aIm + h11x * bRe - h11y * bIm;
  const f2 nbIm = h10x * aIm + h10y * aRe + h11x * bIm + h11y * bRe;
  aRe = naRe; aIm = naIm; bRe = nbRe; bIm = nbIm;
}

__device__ __forceinline__ u32 pk2(float a, float b) {
  __half2 h = __floats2half2_rn(a, b);
  return *(u32*)&h;
}
__device__ __forceinline__ f2 up2(u32 u) {
  __half2 h = *(__half2*)&u;
  return (f2){__low2float(h), __high2float(h)};
}

__global__ __launch_bounds__(NTH) void qc_apply(
    const float* __restrict__ x, const float* __restrict__ wts,
    float* __restrict__ out, int out_size) {
  __shared__ alignas(16) u32 sc[1024];   // 512 blocks x 2 words (f16x2 each)
  __shared__ alignas(16) float sg[NL * NQ * 8];  // gate table, f32

  const int t = threadIdx.x;
  const int sv = blockIdx.x;

  // ---- in-kernel gate build (lanes < 50): transposed U3, h00 real.
  // Same-wave DS ordering: these ds_writes precede all sg reads in program
  // order -> visible without a barrier (validated R12-R14 passes).
  if (t < NL * NQ) {
    const float th = wts[t * 3 + 0], ph = wts[t * 3 + 1], lm = wts[t * 3 + 2];
    const float ch_ = __cosf(0.5f * th), sh = __sinf(0.5f * th);
    const float cl = __cosf(lm), sl = __sinf(lm);
    const float cp = __cosf(ph), sp = __sinf(ph);
    const float cpl = __cosf(ph + lm), spl = __sinf(ph + lm);
    float* G = sg + t * 8;
    G[0] = ch_;       G[1] = 0.0f;
    G[2] = cp * sh;   G[3] = sp * sh;
    G[4] = -cl * sh;  G[5] = -sl * sh;
    G[6] = cpl * ch_; G[7] = spl * ch_;
  }

  // ---- runtime sigma(t) and hoisted address bases (identical to R13).
  int st = t;
#pragma unroll
  for (int q = 0; q < NQ; ++q) {
    const int cb = 9 - q, tb = 9 - ((q + 1) % NQ);
    st ^= ((st >> cb) & 1) << tb;
  }
  const int baseS = cA(st) << 1;                 // sigma-read base (layout A)
  const int tb1 = t << 1;                        // RT1-write base (layout B)
  const int tb2 = (((t & 7) | ((t >> 3) << 6)) ^ ((((t >> 3) & 3)) << 3)) << 1;
  const int tc2 = cC((t & 7) | ((t >> 3) << 6)) << 1;  // RT2-write base (C)
  const int tc3 = cC(t << 3) << 1;               // RT3-read base (C)
  const int ta3 = cA(t << 3) << 1;               // RT3-write base (A)

  static constexpr int SRC[8] = {
      cA(csigma(0 << 6)) << 1, cA(csigma(1 << 6)) << 1, cA(csigma(2 << 6)) << 1,
      cA(csigma(3 << 6)) << 1, cA(csigma(4 << 6)) << 1, cA(csigma(5 << 6)) << 1,
      cA(csigma(6 << 6)) << 1, cA(csigma(7 << 6)) << 1};
#define CB1v(r) ((((r) << 6) ^ (((r) & 3) << 3)) << 1)
  static constexpr int CB1[8] = {CB1v(0), CB1v(1), CB1v(2), CB1v(3),
                                 CB1v(4), CB1v(5), CB1v(6), CB1v(7)};
  static constexpr int CC2[8] = {cC(0 << 3) << 1, cC(1 << 3) << 1,
                                 cC(2 << 3) << 1, cC(3 << 3) << 1,
                                 cC(4 << 3) << 1, cC(5 << 3) << 1,
                                 cC(6 << 3) << 1, cC(7 << 3) << 1};
  static constexpr int CC3[8] = {cC(0) << 1, cC(1) << 1, cC(2) << 1,
                                 cC(3) << 1, cC(4) << 1, cC(5) << 1,
                                 cC(6) << 1, cC(7) << 1};
  static constexpr int CWA[8] = {
      (cA(0) << 1) | 0, (cA(1) << 1) | 1, (cA(2) << 1) | 0, (cA(3) << 1) | 1,
      (cA(4) << 1) | 0, (cA(5) << 1) | 1, (cA(6) << 1) | 0, (cA(7) << 1) | 1};
  static constexpr int CAj[16] = {cA(0),  cA(1),  cA(2),  cA(3),
                                  cA(4),  cA(5),  cA(6),  cA(7),
                                  cA(8),  cA(9),  cA(10), cA(11),
                                  cA(12), cA(13), cA(14), cA(15)};

  // ---- init: x real -> layout A f16 (state s at word 2*A(s)+h(s), h=s0^s9).
  {
    const float* xs = x + (size_t)sv * 1024;
    float4 xv[4];
#pragma unroll
    for (int i4 = 0; i4 < 4; ++i4) xv[i4] = ((const float4*)xs)[4 * t + i4];
    const int ib2 = cA(16 * t) << 1;
    const int ihb = (t >> 5) & 1;  // h(16t) = s9 = t5
#pragma unroll
    for (int j = 0; j < 16; ++j) {
      const float xj = ((const float*)xv)[j];
      const int word = (ib2 ^ (CAj[j] << 1)) | (ihb ^ (j & 1));
      sc[word] = pk2(xj, 0.0f);
    }
  }

  f2 vre[8], vim[8];

  for (int l = NL - 1; l >= 0; --l) {
    const float* gl = sg + l * NQ * 8;   // LDS pointer: uniform ds_read bcast

    // ======== RT1: sigma-gather (layout A); reg bits = SV bits 6-8.
#pragma unroll
    for (int r = 0; r < 8; ++r) {
      const uint2 b = *(const uint2*)&sc[baseS ^ SRC[r]];
      const f2 lo = up2(b.x);
      const f2 hi = up2(b.y);
      vre[r] = (f2){lo.x, hi.x};
      vim[r] = (f2){lo.y, hi.y};
    }
    {
      const int qb[3] = {3, 2, 1};  // reg bit e = SV bit 6+e <-> qubit 3-e
#pragma unroll
      for (int e = 0; e < 3; ++e) {
        const float* G = gl + qb[e] * 8;
        const f4 ga = *(const f4*)&G[0];
        const f4 gb = *(const f4*)&G[4];
        const float h00 = ga.x, h01x = ga.z, h01y = ga.w, h10x = gb.x,
                    h10y = gb.y, h11x = gb.z, h11y = gb.w;
        const int m = 1 << e;
#pragma unroll
        for (int r = 0; r < 8; ++r)
          if (!(r & m))
            pbfly(vre[r], vim[r], vre[r | m], vim[r | m], h00, h01x, h01y,
                  h10x, h10y, h11x, h11y);
      }
    }
#pragma unroll
    for (int r = 0; r < 8; ++r) {
      uint2 b;
      b.x = pk2(vre[r].x, vre[r].y);
      b.y = pk2(vim[r].x, vim[r].y);
      *(uint2*)&sc[tb1 ^ CB1[r]] = b;
    }

    // ======== RT2 (layout B -> C); reg bits = SV bits 3-5.
#pragma unroll
    for (int r = 0; r < 8; ++r) {
      const uint2 b = *(const uint2*)&sc[tb2 ^ (r << 4)];
      vre[r] = up2(b.x);
      vim[r] = up2(b.y);
    }
    {
      const int qb[3] = {6, 5, 4};  // reg bit e = SV bit 3+e <-> qubit 6-e
#pragma unroll
      for (int e = 0; e < 3; ++e) {
        const float* G = gl + qb[e] * 8;
        const f4 ga = *(const f4*)&G[0];
        const f4 gb = *(const f4*)&G[4];
        const float h00 = ga.x, h01x = ga.z, h01y = ga.w, h10x = gb.x,
                    h10y = gb.y, h11x = gb.z, h11y = gb.w;
        const int m = 1 << e;
#pragma unroll
        for (int r = 0; r < 8; ++r)
          if (!(r & m))
            pbfly(vre[r], vim[r], vre[r | m], vim[r | m], h00, h01x, h01y,
                  h10x, h10y, h11x, h11y);
      }
    }
#pragma unroll
    for (int r = 0; r < 8; ++r) {
      uint2 b;
      b.x = pk2(vre[r].x, vre[r].y);
      b.y = pk2(vim[r].x, vim[r].y);
      *(uint2*)&sc[tc2 ^ CC2[r]] = b;
    }

    // ======== RT3 (layout C); reg bits = SV bits 0-2, + bit-9 gate.
#pragma unroll
    for (int r = 0; r < 8; ++r) {
      const uint2 b = *(const uint2*)&sc[tc3 ^ CC3[r]];
      vre[r] = up2(b.x);
      vim[r] = up2(b.y);
    }
    {
      const int qb[3] = {9, 8, 7};  // reg bit e = SV bit e <-> qubit 9-e
#pragma unroll
      for (int e = 0; e < 3; ++e) {
        const float* G = gl + qb[e] * 8;
        const f4 ga = *(const f4*)&G[0];
        const f4 gb = *(const f4*)&G[4];
        const float h00 = ga.x, h01x = ga.z, h01y = ga.w, h10x = gb.x,
                    h10y = gb.y, h11x = gb.z, h11y = gb.w;
        const int m = 1 << e;
#pragma unroll
        for (int r = 0; r < 8; ++r)
          if (!(r & m))
            pbfly(vre[r], vim[r], vre[r | m], vim[r | m], h00, h01x, h01y,
                  h10x, h10y, h11x, h11y);
      }
    }
    {  // qubit-0 gate on SV bit 9 = pack halves (.x <-> .y), scalar form.
      const float* G = gl;
      const f4 ga = *(const f4*)&G[0];
      const f4 gb = *(const f4*)&G[4];
      const float h00 = ga.x, h01x = ga.z, h01y = ga.w, h10x = gb.x,
                  h10y = gb.y, h11x = gb.z, h11y = gb.w;
#pragma unroll
      for (int r = 0; r < 8; ++r) {
        const float re0 = vre[r].x, im0 = vim[r].x;
        const float re1 = vre[r].y, im1 = vim[r].y;
        vre[r].x = h00 * re0 + h01x * re1 - h01y * im1;
        vre[r].y = h10x * re0 - h10y * im0 + h11x * re1 - h11y * im1;
        if (l != 0) {  // vim dead in the final layer (out = Re only)
          vim[r].x = h00 * im0 + h01x * im1 + h01y * re1;
          vim[r].y = h10x * im0 + h10y * re0 + h11x * im1 + h11y * re1;
        }
      }
    }
    if (l != 0) {
#pragma unroll
      for (int r = 0; r < 8; ++r) {
        const int w0 = ta3 ^ CWA[r];
        sc[w0] = pk2(vre[r].x, vim[r].x);
        sc[w0 ^ 513] = pk2(vre[r].y, vim[r].y);
      }
    }
  }

  // ---- output: reals only. .x -> indices 8t..8t+7, .y -> +512.
  const size_t ob = (size_t)sv * 1024 + 8 * t;
  if (ob + 8 <= (size_t)out_size) {
    *(float4*)(out + ob) = make_float4(vre[0].x, vre[1].x, vre[2].x, vre[3].x);
    *(float4*)(out + ob + 4) =
        make_float4(vre[4].x, vre[5].x, vre[6].x, vre[7].x);
  }
  if (ob + 512 + 8 <= (size_t)out_size) {
    *(float4*)(out + ob + 512) =
        make_float4(vre[0].y, vre[1].y, vre[2].y, vre[3].y);
    *(float4*)(out + ob + 516) =
        make_float4(vre[4].y, vre[5].y, vre[6].y, vre[7].y);
  }
}

extern "C" void kernel_launch(void* const* d_in, const int* in_sizes, int n_in,
                              void* d_out, int out_size, void* d_ws, size_t ws_size,
                              hipStream_t stream) {
  const float* x = (const float*)d_in[0];   // [128,16,32,32] f32
  const float* w = (const float*)d_in[1];   // [5,10,3] f32
  float* out = (float*)d_out;               // f32 (real part of complex64)
  const int nstates = in_sizes[0] / 1024;   // 2048
  qc_apply<<<nstates, NTH, 0, stream>>>(x, w, out, out_size);
}